// Round 2
// baseline (235.665 us; speedup 1.0000x reference)
//
#include <hip/hip_runtime.h>

// PCEN: x [32, 256, 4096] fp32. EMA over time (last axis) per row, then
// out = sqrt(x / (m+eps)^0.98 + 2) - sqrt(2).
//
// One block per (b,f) row. 256 threads x 16 elements/thread = 4096.
// Linear-recurrence parallel scan: segment coeff is constant A16 = 0.975^16,
// so Hillis-Steele with constexpr coefficients; cross-wave fixup via LDS.

constexpr int T_LEN  = 4096;
constexpr int NTHR   = 256;
constexpr int PER    = 16;

constexpr float EPSF = 1e-6f;
constexpr float SF   = 0.025f;
constexpr float A1F  = 0.975f;

// exact powers of 0.975 via constexpr repeated squaring
constexpr double dA1    = 0.975;
constexpr double dA2    = dA1 * dA1;
constexpr double dA4    = dA2 * dA2;
constexpr double dA8    = dA4 * dA4;
constexpr double dA16   = dA8 * dA8;      // per-segment coeff (16 steps)
constexpr double dA32   = dA16 * dA16;
constexpr double dA64   = dA32 * dA32;
constexpr double dA128  = dA64 * dA64;
constexpr double dA256  = dA128 * dA128;
constexpr double dA512  = dA256 * dA256;
constexpr double dA1024 = dA512 * dA512;  // per-wave coeff (64 segments)

__global__ __launch_bounds__(NTHR) void pcen_scan_kernel(
    const float* __restrict__ x, float* __restrict__ out)
{
    const int row  = blockIdx.x;
    const long long base = (long long)row * T_LEN;
    const int tid  = threadIdx.x;
    const int lane = tid & 63;
    const int wave = tid >> 6;

    const float4* __restrict__ px   = (const float4*)(x + base);
    float4* __restrict__       pout = (float4*)(out + base);

    // ---- load 16 elements (4 x float4), keep in registers ----
    float4 v0 = px[tid * 4 + 0];
    float4 v1 = px[tid * 4 + 1];
    float4 v2 = px[tid * 4 + 2];
    float4 v3 = px[tid * 4 + 3];
    float xv[PER] = { v0.x, v0.y, v0.z, v0.w,
                      v1.x, v1.y, v1.z, v1.w,
                      v2.x, v2.y, v2.z, v2.w,
                      v3.x, v3.y, v3.z, v3.w };

    // ---- local scan (zero init) -> segment total L_j ----
    float m = 0.0f;
#pragma unroll
    for (int k = 0; k < PER; ++k) m = fmaf(A1F, m, SF * xv[k]);
    float Sv = m;  // inclusive local total

    // ---- wave-level inclusive scan, coeff A16^offset ----
    const float c1  = (float)dA16;
    const float c2  = (float)dA32;
    const float c4  = (float)dA64;
    const float c8  = (float)dA128;
    const float c16 = (float)dA256;
    const float c32 = (float)dA512;
    const float c64 = (float)dA1024;
    float t;
    t = __shfl_up(Sv, 1,  64); if (lane >= 1)  Sv = fmaf(c1,  t, Sv);
    t = __shfl_up(Sv, 2,  64); if (lane >= 2)  Sv = fmaf(c2,  t, Sv);
    t = __shfl_up(Sv, 4,  64); if (lane >= 4)  Sv = fmaf(c4,  t, Sv);
    t = __shfl_up(Sv, 8,  64); if (lane >= 8)  Sv = fmaf(c8,  t, Sv);
    t = __shfl_up(Sv, 16, 64); if (lane >= 16) Sv = fmaf(c16, t, Sv);
    t = __shfl_up(Sv, 32, 64); if (lane >= 32) Sv = fmaf(c32, t, Sv);

    // ---- cross-wave carry (4 waves) ----
    __shared__ float Wt[NTHR / 64];
    if (lane == 63) Wt[wave] = Sv;
    __syncthreads();
    float cw = 0.0f;           // m at end of previous wave's region
    for (int u = 0; u < wave; ++u) cw = fmaf(c64, cw, Wt[u]);

    // global inclusive value: S_glob = S_local + A16^(lane+1) * cw
    // A16^(lane+1) computed exactly from bits of (lane+1)
    {
        int e = lane + 1;
        float f = 1.0f;
        if (e & 1)  f *= c1;
        if (e & 2)  f *= c2;
        if (e & 4)  f *= c4;
        if (e & 8)  f *= c8;
        if (e & 16) f *= c16;
        if (e & 32) f *= c32;
        if (e & 64) f *= c64;
        Sv = fmaf(f, cw, Sv);
    }
    float carry = __shfl_up(Sv, 1, 64);
    if (lane == 0) carry = cw;   // first thread of wave: carry is wave carry

    // ---- second pass: exact EMA from carry + fused epilogue ----
    const float SQRT_D = 1.41421356237309515f;  // sqrt(2.0)
    float r[PER];
    m = carry;
#pragma unroll
    for (int k = 0; k < PER; ++k) {
        m = fmaf(A1F, m, SF * xv[k]);
        // (m+eps)^-0.98 = exp2(-0.98 * log2(m+eps))
        float p = __builtin_amdgcn_exp2f(-0.98f * __builtin_amdgcn_logf(m + EPSF));
        r[k] = __fsqrt_rn(fmaf(xv[k], p, 2.0f)) - SQRT_D;
    }

    pout[tid * 4 + 0] = make_float4(r[0],  r[1],  r[2],  r[3]);
    pout[tid * 4 + 1] = make_float4(r[4],  r[5],  r[6],  r[7]);
    pout[tid * 4 + 2] = make_float4(r[8],  r[9],  r[10], r[11]);
    pout[tid * 4 + 3] = make_float4(r[12], r[13], r[14], r[15]);
}

extern "C" void kernel_launch(void* const* d_in, const int* in_sizes, int n_in,
                              void* d_out, int out_size, void* d_ws, size_t ws_size,
                              hipStream_t stream) {
    const float* x = (const float*)d_in[0];
    float* out = (float*)d_out;
    const int rows = in_sizes[0] / T_LEN;  // 32*256 = 8192
    pcen_scan_kernel<<<dim3(rows), dim3(NTHR), 0, stream>>>(x, out);
}

// Round 3
// 226.633 us; speedup vs baseline: 1.0399x; 1.0399x over previous
//
#include <hip/hip_runtime.h>

// PCEN: x [32, 256, 4096] fp32. EMA over time per row, then
// out = sqrt(x / (m+eps)^0.98 + 2) - sqrt(2).
//
// One block per (b,f) row. 1024 threads x 4 elements (one float4) each.
// Perfectly coalesced: lane i loads/stores float4 #i (16 B/lane contiguous).
// Linear-recurrence parallel scan: per-thread segment coeff A4 = 0.975^4;
// Hillis-Steele wave scan with constexpr coeffs A4^(2^d); 16-wave fixup via LDS.

constexpr int T_LEN  = 4096;
constexpr int NTHR   = 1024;
constexpr int PER    = 4;

constexpr float EPSF = 1e-6f;
constexpr float SF   = 0.025f;
constexpr float A1F  = 0.975f;

// exact powers of 0.975 via constexpr repeated squaring
constexpr double dA1   = 0.975;
constexpr double dA2   = dA1 * dA1;
constexpr double dA4   = dA2 * dA2;     // per-thread segment coeff (4 steps)
constexpr double dA8   = dA4 * dA4;
constexpr double dA16  = dA8 * dA8;
constexpr double dA32  = dA16 * dA16;
constexpr double dA64  = dA32 * dA32;
constexpr double dA128 = dA64 * dA64;
constexpr double dA256 = dA128 * dA128; // per-wave coeff (64 segments x 4)

__global__ __launch_bounds__(NTHR) void pcen_scan_kernel(
    const float* __restrict__ x, float* __restrict__ out)
{
    const int row  = blockIdx.x;
    const long long base = (long long)row * T_LEN;
    const int tid  = threadIdx.x;
    const int lane = tid & 63;
    const int wave = tid >> 6;

    const float4* __restrict__ px   = (const float4*)(x + base);
    float4* __restrict__       pout = (float4*)(out + base);

    // ---- coalesced load: lane i -> float4 #i ----
    float4 v = px[tid];
    float xv[PER] = { v.x, v.y, v.z, v.w };

    // ---- local scan (zero init) -> segment total ----
    float m = 0.0f;
#pragma unroll
    for (int k = 0; k < PER; ++k) m = fmaf(A1F, m, SF * xv[k]);
    float Sv = m;  // inclusive local total

    // ---- wave-level inclusive scan, coeff A4^offset ----
    const float c1  = (float)dA4;
    const float c2  = (float)dA8;
    const float c4  = (float)dA16;
    const float c8  = (float)dA32;
    const float c16 = (float)dA64;
    const float c32 = (float)dA128;
    const float c64 = (float)dA256;
    float t;
    t = __shfl_up(Sv, 1,  64); if (lane >= 1)  Sv = fmaf(c1,  t, Sv);
    t = __shfl_up(Sv, 2,  64); if (lane >= 2)  Sv = fmaf(c2,  t, Sv);
    t = __shfl_up(Sv, 4,  64); if (lane >= 4)  Sv = fmaf(c4,  t, Sv);
    t = __shfl_up(Sv, 8,  64); if (lane >= 8)  Sv = fmaf(c8,  t, Sv);
    t = __shfl_up(Sv, 16, 64); if (lane >= 16) Sv = fmaf(c16, t, Sv);
    t = __shfl_up(Sv, 32, 64); if (lane >= 32) Sv = fmaf(c32, t, Sv);

    // ---- cross-wave carry (16 waves) ----
    __shared__ float Wt[NTHR / 64];
    if (lane == 63) Wt[wave] = Sv;
    __syncthreads();
    float cw = 0.0f;           // m at end of previous wave's region
    for (int u = 0; u < wave; ++u) cw = fmaf(c64, cw, Wt[u]);

    // global inclusive value: S_glob = S_local + A4^(lane+1) * cw
    {
        int e = lane + 1;      // 1..64
        float f = 1.0f;
        if (e & 1)  f *= c1;
        if (e & 2)  f *= c2;
        if (e & 4)  f *= c4;
        if (e & 8)  f *= c8;
        if (e & 16) f *= c16;
        if (e & 32) f *= c32;
        if (e & 64) f *= c64;
        Sv = fmaf(f, cw, Sv);
    }
    float carry = __shfl_up(Sv, 1, 64);
    if (lane == 0) carry = cw;   // first thread of wave: carry is wave carry

    // ---- second pass: exact EMA from carry + fused epilogue ----
    const float SQRT_D = 1.41421356237309515f;  // sqrt(2.0)
    float r[PER];
    m = carry;
#pragma unroll
    for (int k = 0; k < PER; ++k) {
        m = fmaf(A1F, m, SF * xv[k]);
        // (m+eps)^-0.98 = exp2(-0.98 * log2(m+eps))
        float p = __builtin_amdgcn_exp2f(-0.98f * __builtin_amdgcn_logf(m + EPSF));
        r[k] = __fsqrt_rn(fmaf(xv[k], p, 2.0f)) - SQRT_D;
    }

    // ---- coalesced store ----
    pout[tid] = make_float4(r[0], r[1], r[2], r[3]);
}

extern "C" void kernel_launch(void* const* d_in, const int* in_sizes, int n_in,
                              void* d_out, int out_size, void* d_ws, size_t ws_size,
                              hipStream_t stream) {
    const float* x = (const float*)d_in[0];
    float* out = (float*)d_out;
    const int rows = in_sizes[0] / T_LEN;  // 32*256 = 8192
    pcen_scan_kernel<<<dim3(rows), dim3(NTHR), 0, stream>>>(x, out);
}